// Round 22
// baseline (3020.146 us; speedup 1.0000x reference)
//
#include <hip/hip_runtime.h>

#define TT 512
#define HH 256

typedef _Float16 half2t __attribute__((ext_vector_type(2)));

// fp16-pair dot with fp32 accumulate (v_dot2_f32_f16 when available).
__device__ __forceinline__ float dot2acc(unsigned w, unsigned h, float acc) {
#if __has_builtin(__builtin_amdgcn_fdot2)
    return __builtin_amdgcn_fdot2(__builtin_bit_cast(half2t, w),
                                  __builtin_bit_cast(half2t, h), acc, false);
#else
    union U { unsigned u; _Float16 f[2]; };
    U uw, uh; uw.u = w; uh.u = h;
    acc = __builtin_fmaf((float)uw.f[0], (float)uh.f[0], acc);
    acc = __builtin_fmaf((float)uw.f[1], (float)uh.f[1], acc);
    return acc;
#endif
}

__device__ __forceinline__ unsigned packh2(float a, float b) {
    union U { _Float16 f[2]; unsigned u; } r;
    r.f[0] = (_Float16)a; r.f[1] = (_Float16)b;   // RNE conversion
    return r.u;
}

#define AGPR_W(dst, src) \
    asm volatile("v_accvgpr_write_b32 %0, %1" : "=a"(dst) : "v"(src))
#define AGPR_R(dst, src) \
    asm("v_accvgpr_read_b32 %0, %1" : "=v"(dst) : "a"(src))

// 4-lane (quad) butterfly sum via DPP quad_perm -- pure VALU, no LDS.
__device__ __forceinline__ float qsum4(float v) {
    int a = __builtin_amdgcn_mov_dpp(__builtin_bit_cast(int, v), 0xB1, 0xF, 0xF, true);
    float r = v + __builtin_bit_cast(float, a);
    int b = __builtin_amdgcn_mov_dpp(__builtin_bit_cast(int, r), 0x4E, 0xF, 0xF, true);
    return r + __builtin_bit_cast(float, b);
}

// consume streamed tail block U (literal!) into gate accumulators
#define TCONS(TQ, U)                                                          \
    do {                                                                      \
        acc[(4*(U)+0)/9] = dot2acc((TQ).x, hw[(4*(U)+0)%9], acc[(4*(U)+0)/9]); \
        acc[(4*(U)+1)/9] = dot2acc((TQ).y, hw[(4*(U)+1)%9], acc[(4*(U)+1)/9]); \
        acc[(4*(U)+2)/9] = dot2acc((TQ).z, hw[(4*(U)+2)%9], acc[(4*(U)+2)/9]); \
        acc[(4*(U)+3)/9] = dot2acc((TQ).w, hw[(4*(U)+3)%9], acc[(4*(U)+3)/9]); \
    } while (0)

// C=1, 1024 threads/wg, one wg per batch (128 wgs). Thread = (element
// e = j>>2, K-chunk s = j&3); rows {e,256+e,512+e,768+e} x K[64s..64s+64)
// = 128 packed fp16 words: 64 AGPR + 28 arch + 36 STREAMED FROM GLOBAL.
// R22: the 36-word tail moves from LDS (9 b128/wave on the CU-serial LDS
// pipe, ~12cyc each -- the R15-R21 bottleneck) to the idle vmem pipe:
// packed once into d_ws (batch-independent, 147KB total, all wgs write
// identical values -- benign race), streamed per step (L2-hot, shared by
// all 16 CUs/XCD). LDS instrs/wave: 17 -> ~10. 100KB DYNAMIC shared memory
// (launch param, not DCE-able) keeps 1 wg/CU.
__global__ __launch_bounds__(1024)
__attribute__((amdgpu_waves_per_eu(4, 4)))
void lstm_single(
    const float* __restrict__ x,      // [B,T]
    const float* __restrict__ W_ih,   // [1024]
    const float* __restrict__ W_hh,   // [1024,256]
    const float* __restrict__ b_ih,   // [1024]
    const float* __restrict__ b_hh,   // [1024]
    const float* __restrict__ W1,     // [128,256]
    const float* __restrict__ b1,     // [128]
    const float* __restrict__ W2,     // [128]
    const float* __restrict__ b2,     // [1]
    float* __restrict__ out,          // [B]
    uint4* __restrict__ wt)           // [1024*9] packed fp16 tail (d_ws)
{
    const int b = blockIdx.x;
    const int j = threadIdx.x;        // 0..1023
    const int e = j >> 2;             // element 0..255
    const int s = j & 3;              // K-chunk (64 fp32) 0..3

    __shared__ __align__(16) unsigned hbuf[2][140];   // h fp16 words, padded slices
    __shared__ float h32[HH];                         // 1 KB (epilogue)
    __shared__ float x_lds[TT];                       // 2 KB
    __shared__ float red[128];                        // 512 B

    // ---- stage weights: per row g: words 0..15 -> AGPR, 16..22 -> arch
    unsigned wag[64];
    unsigned wv[28];
    #pragma unroll
    for (int g = 0; g < 4; ++g) {
        const float* pR = W_hh + (size_t)(g * 256 + e) * HH + 64 * s;
        #pragma unroll
        for (int k = 0; k < 16; ++k) {
            unsigned pw = packh2(pR[2 * k], pR[2 * k + 1]);
            AGPR_W(wag[g * 16 + k], pw);
        }
        #pragma unroll
        for (int k = 0; k < 7; ++k)
            wv[g * 7 + k] = packh2(pR[2 * (16 + k)], pR[2 * (16 + k) + 1]);
    }
    #pragma unroll
    for (int k = 0; k < 28; ++k)
        asm volatile("" : "+v"(wv[k]));

    // ---- pack tail words 23..31 of each row -> d_ws (identical across wgs)
    #pragma unroll
    for (int u = 0; u < 9; ++u) {
        uint4 v;
        {
            const int m = 4 * u + 0, g = m / 9, k = 23 + m % 9;
            const float* pR = W_hh + (size_t)(g * 256 + e) * HH + 64 * s;
            v.x = packh2(pR[2 * k], pR[2 * k + 1]);
        }
        {
            const int m = 4 * u + 1, g = m / 9, k = 23 + m % 9;
            const float* pR = W_hh + (size_t)(g * 256 + e) * HH + 64 * s;
            v.y = packh2(pR[2 * k], pR[2 * k + 1]);
        }
        {
            const int m = 4 * u + 2, g = m / 9, k = 23 + m % 9;
            const float* pR = W_hh + (size_t)(g * 256 + e) * HH + 64 * s;
            v.z = packh2(pR[2 * k], pR[2 * k + 1]);
        }
        {
            const int m = 4 * u + 3, g = m / 9, k = 23 + m % 9;
            const float* pR = W_hh + (size_t)(g * 256 + e) * HH + 64 * s;
            v.w = packh2(pR[2 * k], pR[2 * k + 1]);
        }
        wt[(size_t)j * 9 + u] = v;
    }

    // cell constants (quad-redundant)
    float wih[4], bias[4];
    #pragma unroll
    for (int g = 0; g < 4; ++g) {
        const int R = g * 256 + e;
        wih[g]  = W_ih[R];
        bias[g] = b_ih[R] + b_hh[R];
    }

    if (j < TT) x_lds[j] = x[(size_t)b * TT + j];
    if (j < 140) { hbuf[0][j] = 0u; hbuf[1][j] = 0u; }
    float c = 0.0f;                   // cell state of element e (quad-redundant)
    __syncthreads();                  // also drains vmcnt: wt[] visible to self

    const uint4* wtp = wt + (size_t)j * 9;

    for (int t = 0; t < TT; ++t) {
        const int p  = t & 1;
        const int pn = p ^ 1;
        // ---- issue first 4 tail loads (h-independent; L2 latency hides
        //      under the AGPR dot section)
        uint4 tq0 = wtp[0];
        uint4 tq1 = wtp[1];
        uint4 tq2 = wtp[2];
        uint4 tq3 = wtp[3];

        const float xv = x_lds[t];
        const unsigned* hb = &hbuf[p][36 * s];
        float acc[4] = {0.f, 0.f, 0.f, 0.f};

        // ---- row words 0..15 (AGPR): h blocks 0..3
        #pragma unroll
        for (int i = 0; i < 4; ++i) {
            uint4 hq = *reinterpret_cast<const uint4*>(&hb[4 * i]);
            #pragma unroll
            for (int g = 0; g < 4; ++g) {
                unsigned w0, w1, w2, w3;
                AGPR_R(w0, wag[g * 16 + 4 * i + 0]);
                AGPR_R(w1, wag[g * 16 + 4 * i + 1]);
                AGPR_R(w2, wag[g * 16 + 4 * i + 2]);
                AGPR_R(w3, wag[g * 16 + 4 * i + 3]);
                acc[g] = dot2acc(w0, hq.x, acc[g]);
                acc[g] = dot2acc(w1, hq.y, acc[g]);
                acc[g] = dot2acc(w2, hq.z, acc[g]);
                acc[g] = dot2acc(w3, hq.w, acc[g]);
            }
        }
        // ---- row words 16..22 (arch): h blocks 4,5
        uint4 h4 = *reinterpret_cast<const uint4*>(&hb[16]);
        uint4 h5 = *reinterpret_cast<const uint4*>(&hb[20]);
        #pragma unroll
        for (int g = 0; g < 4; ++g) {
            acc[g] = dot2acc(wv[g * 7 + 0], h4.x, acc[g]);
            acc[g] = dot2acc(wv[g * 7 + 1], h4.y, acc[g]);
            acc[g] = dot2acc(wv[g * 7 + 2], h4.z, acc[g]);
            acc[g] = dot2acc(wv[g * 7 + 3], h4.w, acc[g]);
            acc[g] = dot2acc(wv[g * 7 + 4], h5.x, acc[g]);
            acc[g] = dot2acc(wv[g * 7 + 5], h5.y, acc[g]);
            acc[g] = dot2acc(wv[g * 7 + 6], h5.z, acc[g]);
        }
        // ---- row words 23..31 (streamed tail): h words 23..31
        uint4 h6 = *reinterpret_cast<const uint4*>(&hb[24]);
        uint4 h7 = *reinterpret_cast<const uint4*>(&hb[28]);
        const unsigned hw[9] = {h5.w, h6.x, h6.y, h6.z, h6.w,
                                h7.x, h7.y, h7.z, h7.w};
        TCONS(tq0, 0); tq0 = wtp[4];
        TCONS(tq1, 1); tq1 = wtp[5];
        TCONS(tq2, 2); tq2 = wtp[6];
        TCONS(tq3, 3); tq3 = wtp[7];
        TCONS(tq0, 4); tq0 = wtp[8];
        TCONS(tq1, 5);
        TCONS(tq2, 6);
        TCONS(tq3, 7);
        TCONS(tq0, 8);

        // ---- quad butterfly: all 4 lanes get full gate sums (pure VALU)
        float gi = qsum4(acc[0]) + __builtin_fmaf(xv, wih[0], bias[0]);
        float gf = qsum4(acc[1]) + __builtin_fmaf(xv, wih[1], bias[1]);
        float gg = qsum4(acc[2]) + __builtin_fmaf(xv, wih[2], bias[2]);
        float go = qsum4(acc[3]) + __builtin_fmaf(xv, wih[3], bias[3]);

        // ---- cell update (quad-redundant, no idle waves)
        gi = __builtin_amdgcn_rcpf(1.f + __expf(-gi));
        gf = __builtin_amdgcn_rcpf(1.f + __expf(-gf));
        go = __builtin_amdgcn_rcpf(1.f + __expf(-go));
        gg = 2.f * __builtin_amdgcn_rcpf(1.f + __expf(-2.f * gg)) - 1.f;
        c = __builtin_fmaf(gf, c, gi * gg);
        float th = 2.f * __builtin_amdgcn_rcpf(1.f + __expf(-2.f * c)) - 1.f;
        float hn = go * th;

        // ---- publish: one writer per quad (s == e>>6)
        if ((e >> 6) == s)
            reinterpret_cast<unsigned short*>(&hbuf[pn][0])[e + 8 * s] =
                __builtin_bit_cast(unsigned short, (_Float16)hn);
        if (s == 0) h32[e] = hn;
        __syncthreads();              // the ONLY barrier per step
    }

    // ---- epilogue MLP: y = relu(h @ W1.T + b1) @ W2.T + b2
    if (j < 128) {
        const float4* w1p = reinterpret_cast<const float4*>(W1 + (size_t)j * HH);
        const float4* hp  = reinterpret_cast<const float4*>(h32);
        float s0 = 0.f, s1 = 0.f, s2 = 0.f, s3 = 0.f;
        #pragma unroll
        for (int k = 0; k < 64; ++k) {
            float4 wv4 = w1p[k], hv = hp[k];
            s0 = __builtin_fmaf(wv4.x, hv.x, s0);
            s1 = __builtin_fmaf(wv4.y, hv.y, s1);
            s2 = __builtin_fmaf(wv4.z, hv.z, s2);
            s3 = __builtin_fmaf(wv4.w, hv.w, s3);
        }
        float rv = fmaxf((s0 + s1) + (s2 + s3) + b1[j], 0.f);
        red[j] = rv * W2[j];
    }
    __syncthreads();
    if (j == 0) {
        float y = b2[0];
        #pragma unroll 4
        for (int k = 0; k < 128; ++k) y += red[k];
        out[b] = y;
    }
}

extern "C" void kernel_launch(void* const* d_in, const int* in_sizes, int n_in,
                              void* d_out, int out_size, void* d_ws, size_t ws_size,
                              hipStream_t stream) {
    const float* x    = (const float*)d_in[0];
    const float* W_ih = (const float*)d_in[1];
    const float* W_hh = (const float*)d_in[2];
    const float* b_ih = (const float*)d_in[3];
    const float* b_hh = (const float*)d_in[4];
    const float* W1   = (const float*)d_in[5];
    const float* b1   = (const float*)d_in[6];
    const float* W2   = (const float*)d_in[7];
    const float* b2   = (const float*)d_in[8];
    float* out = (float*)d_out;
    uint4* wt  = (uint4*)d_ws;        // 1024*9*16 = 147456 B

    // 100 KB dynamic LDS: occupancy clamp to 1 wg/CU (launch parameter --
    // cannot be optimized away, unlike a dummy static array)
    lstm_single<<<128, 1024, 100 * 1024, stream>>>(x, W_ih, W_hh, b_ih, b_hh,
                                                   W1, b1, W2, b2, out, wt);
}

// Round 23
// 1187.769 us; speedup vs baseline: 2.5427x; 2.5427x over previous
//
#include <hip/hip_runtime.h>

#define TT 512
#define HH 256

typedef _Float16 half2t __attribute__((ext_vector_type(2)));

// fp16-pair dot with fp32 accumulate (v_dot2_f32_f16 when available).
__device__ __forceinline__ float dot2acc(unsigned w, unsigned h, float acc) {
#if __has_builtin(__builtin_amdgcn_fdot2)
    return __builtin_amdgcn_fdot2(__builtin_bit_cast(half2t, w),
                                  __builtin_bit_cast(half2t, h), acc, false);
#else
    union U { unsigned u; _Float16 f[2]; };
    U uw, uh; uw.u = w; uh.u = h;
    acc = __builtin_fmaf((float)uw.f[0], (float)uh.f[0], acc);
    acc = __builtin_fmaf((float)uw.f[1], (float)uh.f[1], acc);
    return acc;
#endif
}

__device__ __forceinline__ unsigned packh2(float a, float b) {
    union U { _Float16 f[2]; unsigned u; } r;
    r.f[0] = (_Float16)a; r.f[1] = (_Float16)b;   // RNE conversion
    return r.u;
}

#define AGPR_W(dst, src) \
    asm volatile("v_accvgpr_write_b32 %0, %1" : "=a"(dst) : "v"(src))
#define AGPR_R(dst, src) \
    asm("v_accvgpr_read_b32 %0, %1" : "=v"(dst) : "a"(src))

// 4-lane (quad) butterfly sum via DPP quad_perm -- pure VALU, no LDS.
__device__ __forceinline__ float qsum4(float v) {
    int a = __builtin_amdgcn_mov_dpp(__builtin_bit_cast(int, v), 0xB1, 0xF, 0xF, true);
    float r = v + __builtin_bit_cast(float, a);
    int b = __builtin_amdgcn_mov_dpp(__builtin_bit_cast(int, r), 0x4E, 0xF, 0xF, true);
    return r + __builtin_bit_cast(float, b);
}

// consume tail block U (literal!) into gate accumulators
#define TCONS(TQ, U)                                                           \
    do {                                                                       \
        acc[(4*(U)+0)/9] = dot2acc((TQ).x, hw[(4*(U)+0)%9], acc[(4*(U)+0)/9]); \
        acc[(4*(U)+1)/9] = dot2acc((TQ).y, hw[(4*(U)+1)%9], acc[(4*(U)+1)/9]); \
        acc[(4*(U)+2)/9] = dot2acc((TQ).z, hw[(4*(U)+2)%9], acc[(4*(U)+2)/9]); \
        acc[(4*(U)+3)/9] = dot2acc((TQ).w, hw[(4*(U)+3)%9], acc[(4*(U)+3)/9]); \
    } while (0)

// C=1, 1024 threads/wg, one wg per batch (128 wgs, plain launch).
// Thread = (element e = j>>2, K-chunk s = j&3); rows {e,256+e,512+e,768+e}
// x K[64s..64s+64) = 128 packed fp16 words: 64 AGPR + 28 arch + 36 LDS.
// R21 skeleton (1 barrier/step, DPP quad reduce, quad-redundant cell).
//
// R23 change (single lever): explicit issue-early/consume-late LDS schedule.
// All 8 h-block reads (broadcast, cheap) + the first 4 tail-weight b128
// reads (the pipe hogs) are issued at the TOP of the step; the AGPR dot
// section (128 pure-VALU dot2) runs while returns stream in; tails are
// consumed last with a rolling reload. R21 interleaved each ds_read with
// its consumer -> lgkmcnt-wait per use -> VALU and LDS pipes ran serially
// (2.29us/step at VALUBusy 37%).
__global__ __launch_bounds__(1024)
__attribute__((amdgpu_waves_per_eu(4, 4)))
void lstm_single(
    const float* __restrict__ x,      // [B,T]
    const float* __restrict__ W_ih,   // [1024]
    const float* __restrict__ W_hh,   // [1024,256]
    const float* __restrict__ b_ih,   // [1024]
    const float* __restrict__ b_hh,   // [1024]
    const float* __restrict__ W1,     // [128,256]
    const float* __restrict__ b1,     // [128]
    const float* __restrict__ W2,     // [128]
    const float* __restrict__ b2,     // [1]
    float* __restrict__ out)          // [B]
{
    const int b = blockIdx.x;
    const int j = threadIdx.x;        // 0..1023
    const int e = j >> 2;             // element 0..255
    const int s = j & 3;              // K-chunk (64 fp32) 0..3

    __shared__ __align__(16) unsigned wl[9][1024][4]; // 144 KB weight tail
    __shared__ __align__(16) unsigned hbuf[2][140];   // h fp16 words, padded slices
    __shared__ float h32[HH];                         // 1 KB (epilogue)
    __shared__ float x_lds[TT];                       // 2 KB
    __shared__ float red[128];                        // 512 B
    // total ~148.6 KB -> 1 wg/CU

    // ---- stage weights: per row g: words 0..15 -> AGPR, 16..22 -> arch,
    //      23..31 -> LDS tail (m = g*9 + (k-23), packed as 9 uint4)
    unsigned wag[64];
    unsigned wv[28];
    #pragma unroll
    for (int g = 0; g < 4; ++g) {
        const float* pR = W_hh + (size_t)(g * 256 + e) * HH + 64 * s;
        #pragma unroll
        for (int k = 0; k < 16; ++k) {
            unsigned pw = packh2(pR[2 * k], pR[2 * k + 1]);
            AGPR_W(wag[g * 16 + k], pw);
        }
        #pragma unroll
        for (int k = 0; k < 7; ++k)
            wv[g * 7 + k] = packh2(pR[2 * (16 + k)], pR[2 * (16 + k) + 1]);
    }
    #pragma unroll
    for (int k = 0; k < 28; ++k)
        asm volatile("" : "+v"(wv[k]));
    #pragma unroll
    for (int u = 0; u < 9; ++u) {
        #pragma unroll
        for (int c2 = 0; c2 < 4; ++c2) {
            const int m = 4 * u + c2;            // 0..35
            const int g = m / 9, k = 23 + m % 9; // row, row-word
            const float* pR = W_hh + (size_t)(g * 256 + e) * HH + 64 * s;
            wl[u][j][c2] = packh2(pR[2 * k], pR[2 * k + 1]);
        }
    }

    // cell constants (all 4 quad lanes redundant)
    float wih[4], bias[4];
    #pragma unroll
    for (int g = 0; g < 4; ++g) {
        const int R = g * 256 + e;
        wih[g]  = W_ih[R];
        bias[g] = b_ih[R] + b_hh[R];
    }

    if (j < TT) x_lds[j] = x[(size_t)b * TT + j];
    if (j < 140) { hbuf[0][j] = 0u; hbuf[1][j] = 0u; }
    float c = 0.0f;                   // cell state of element e (quad-redundant)
    __syncthreads();

    for (int t = 0; t < TT; ++t) {
        const int p  = t & 1;
        const int pn = p ^ 1;
        const float xv = x_lds[t];
        const unsigned* hb = &hbuf[p][36 * s];

        // ================= issue phase: all h reads + first 4 tail reads ==
        uint4 h0 = *reinterpret_cast<const uint4*>(&hb[0]);
        uint4 h1 = *reinterpret_cast<const uint4*>(&hb[4]);
        uint4 h2 = *reinterpret_cast<const uint4*>(&hb[8]);
        uint4 h3 = *reinterpret_cast<const uint4*>(&hb[12]);
        uint4 h4 = *reinterpret_cast<const uint4*>(&hb[16]);
        uint4 h5 = *reinterpret_cast<const uint4*>(&hb[20]);
        uint4 h6 = *reinterpret_cast<const uint4*>(&hb[24]);
        uint4 h7 = *reinterpret_cast<const uint4*>(&hb[28]);
        uint4 tq0 = *reinterpret_cast<const uint4*>(&wl[0][j][0]);
        uint4 tq1 = *reinterpret_cast<const uint4*>(&wl[1][j][0]);
        uint4 tq2 = *reinterpret_cast<const uint4*>(&wl[2][j][0]);
        uint4 tq3 = *reinterpret_cast<const uint4*>(&wl[3][j][0]);

        float acc[4] = {0.f, 0.f, 0.f, 0.f};

        // ========== AGPR dot section (pure VALU; LDS returns stream in) ===
        {
            uint4 hqs[4] = {h0, h1, h2, h3};
            #pragma unroll
            for (int i = 0; i < 4; ++i) {
                uint4 hq = hqs[i];
                #pragma unroll
                for (int g = 0; g < 4; ++g) {
                    unsigned w0, w1, w2, w3;
                    AGPR_R(w0, wag[g * 16 + 4 * i + 0]);
                    AGPR_R(w1, wag[g * 16 + 4 * i + 1]);
                    AGPR_R(w2, wag[g * 16 + 4 * i + 2]);
                    AGPR_R(w3, wag[g * 16 + 4 * i + 3]);
                    acc[g] = dot2acc(w0, hq.x, acc[g]);
                    acc[g] = dot2acc(w1, hq.y, acc[g]);
                    acc[g] = dot2acc(w2, hq.z, acc[g]);
                    acc[g] = dot2acc(w3, hq.w, acc[g]);
                }
            }
        }
        // ========== arch section: h blocks 4,5 =============================
        #pragma unroll
        for (int g = 0; g < 4; ++g) {
            acc[g] = dot2acc(wv[g * 7 + 0], h4.x, acc[g]);
            acc[g] = dot2acc(wv[g * 7 + 1], h4.y, acc[g]);
            acc[g] = dot2acc(wv[g * 7 + 2], h4.z, acc[g]);
            acc[g] = dot2acc(wv[g * 7 + 3], h4.w, acc[g]);
            acc[g] = dot2acc(wv[g * 7 + 4], h5.x, acc[g]);
            acc[g] = dot2acc(wv[g * 7 + 5], h5.y, acc[g]);
            acc[g] = dot2acc(wv[g * 7 + 6], h5.z, acc[g]);
        }
        // ========== tail section: rolling consume/reload ===================
        const unsigned hw[9] = {h5.w, h6.x, h6.y, h6.z, h6.w,
                                h7.x, h7.y, h7.z, h7.w};
        TCONS(tq0, 0); tq0 = *reinterpret_cast<const uint4*>(&wl[4][j][0]);
        TCONS(tq1, 1); tq1 = *reinterpret_cast<const uint4*>(&wl[5][j][0]);
        TCONS(tq2, 2); tq2 = *reinterpret_cast<const uint4*>(&wl[6][j][0]);
        TCONS(tq3, 3); tq3 = *reinterpret_cast<const uint4*>(&wl[7][j][0]);
        TCONS(tq0, 4); tq0 = *reinterpret_cast<const uint4*>(&wl[8][j][0]);
        TCONS(tq1, 5);
        TCONS(tq2, 6);
        TCONS(tq3, 7);
        TCONS(tq0, 8);

        // ---- quad butterfly: all 4 lanes get full gate sums (pure VALU)
        float gi = qsum4(acc[0]) + __builtin_fmaf(xv, wih[0], bias[0]);
        float gf = qsum4(acc[1]) + __builtin_fmaf(xv, wih[1], bias[1]);
        float gg = qsum4(acc[2]) + __builtin_fmaf(xv, wih[2], bias[2]);
        float go = qsum4(acc[3]) + __builtin_fmaf(xv, wih[3], bias[3]);

        // ---- cell update (quad-redundant, no idle waves)
        gi = __builtin_amdgcn_rcpf(1.f + __expf(-gi));
        gf = __builtin_amdgcn_rcpf(1.f + __expf(-gf));
        go = __builtin_amdgcn_rcpf(1.f + __expf(-go));
        gg = 2.f * __builtin_amdgcn_rcpf(1.f + __expf(-2.f * gg)) - 1.f;
        c = __builtin_fmaf(gf, c, gi * gg);
        float th = 2.f * __builtin_amdgcn_rcpf(1.f + __expf(-2.f * c)) - 1.f;
        float hn = go * th;

        // ---- publish: one writer per quad (s == e>>6)
        if ((e >> 6) == s)
            reinterpret_cast<unsigned short*>(&hbuf[pn][0])[e + 8 * s] =
                __builtin_bit_cast(unsigned short, (_Float16)hn);
        if (s == 0) h32[e] = hn;
        __syncthreads();              // the ONLY barrier per step
    }

    // ---- epilogue MLP: y = relu(h @ W1.T + b1) @ W2.T + b2
    if (j < 128) {
        const float4* w1p = reinterpret_cast<const float4*>(W1 + (size_t)j * HH);
        const float4* hp  = reinterpret_cast<const float4*>(h32);
        float s0 = 0.f, s1 = 0.f, s2 = 0.f, s3 = 0.f;
        #pragma unroll
        for (int k = 0; k < 64; ++k) {
            float4 wv4 = w1p[k], hv = hp[k];
            s0 = __builtin_fmaf(wv4.x, hv.x, s0);
            s1 = __builtin_fmaf(wv4.y, hv.y, s1);
            s2 = __builtin_fmaf(wv4.z, hv.z, s2);
            s3 = __builtin_fmaf(wv4.w, hv.w, s3);
        }
        float rv = fmaxf((s0 + s1) + (s2 + s3) + b1[j], 0.f);
        red[j] = rv * W2[j];
    }
    __syncthreads();
    if (j == 0) {
        float y = b2[0];
        #pragma unroll 4
        for (int k = 0; k < 128; ++k) y += red[k];
        out[b] = y;
    }
}

extern "C" void kernel_launch(void* const* d_in, const int* in_sizes, int n_in,
                              void* d_out, int out_size, void* d_ws, size_t ws_size,
                              hipStream_t stream) {
    const float* x    = (const float*)d_in[0];
    const float* W_ih = (const float*)d_in[1];
    const float* W_hh = (const float*)d_in[2];
    const float* b_ih = (const float*)d_in[3];
    const float* b_hh = (const float*)d_in[4];
    const float* W1   = (const float*)d_in[5];
    const float* b1   = (const float*)d_in[6];
    const float* W2   = (const float*)d_in[7];
    const float* b2   = (const float*)d_in[8];
    float* out = (float*)d_out;

    lstm_single<<<128, 1024, 0, stream>>>(x, W_ih, W_hh, b_ih, b_hh,
                                          W1, b1, W2, b2, out);
}